// Round 1
// baseline (21370.972 us; speedup 1.0000x reference)
//
#include <hip/hip_runtime.h>
#include <math.h>

// LSTM: T=512, B=64, H=1024, L=2, fp32.
// Diagonal schedule: step d runs layer0@t=d and layer1@t=(d-1) concurrently.
// Per step: split-K GEMM (K=2048 -> 16 slices) writes partials, reduce kernel
// sums partials + bias and applies the fused LSTM cell elementwise.

#define T_STEPS 512
#define BATCH   64
#define HID     1024
#define G4      4096         // 4*HID
#define KTOT    2048         // 2*HID
#define BN      64
#define BK      32
#define KSLICES 16
#define KSPAN   128          // KTOT/KSLICES
#define NTILES  64           // G4/BN
#define STATE   (BATCH*HID)  // 65536
#define PART_L  ((size_t)KSLICES*BATCH*G4)

__device__ __forceinline__ float sigf(float x) { return 1.0f / (1.0f + __expf(-x)); }

// ---------------------------------------------------------------------------
// GEMM: gates_partial[layer][ks][b][j] = sum_{k in slice} A[b][k] * W[k][j]
// A = concat(Ax, Ah) along k (k<1024 from Ax, else Ah). 2048 WGs:
// wg<1024 -> layer0, else layer1. lwg = (ntile, kslice).
// ---------------------------------------------------------------------------
__global__ __launch_bounds__(256) void gemm_step(
    const float* __restrict__ A0x, const float* __restrict__ A0h,
    const float* __restrict__ W0,
    const float* __restrict__ A1x, const float* __restrict__ A1h,
    const float* __restrict__ W1,
    float* __restrict__ part, int act0, int act1)
{
    const int wg = blockIdx.x;
    const int layer = (wg >= NTILES * KSLICES) ? 1 : 0;
    if (layer ? !act1 : !act0) return;

    const int lwg   = wg & (NTILES * KSLICES - 1);
    const int ntile = lwg & (NTILES - 1);
    const int ks    = lwg >> 6;

    const float* __restrict__ Ax = layer ? A1x : A0x;
    const float* __restrict__ Ah = layer ? A1h : A0h;
    const float* __restrict__ W  = layer ? W1  : W0;
    float* __restrict__ P = part + (size_t)layer * PART_L + (size_t)ks * (BATCH * G4);

    const float* __restrict__ Asrc = (ks < 8) ? Ax : Ah;
    const int k0  = (ks < 8) ? ks * KSPAN : ks * KSPAN - HID;  // col base in Asrc
    const int kw0 = ks * KSPAN;                                // row base in W
    const int n0  = ntile * BN;

    // At transposed [kk][b] so fragment reads are contiguous ds_read_b128.
    // Row stride 68 floats = 272 B = 17*16 B -> 16B-aligned rows, conflict-light.
    __shared__ __align__(16) float At[BK][68];
    __shared__ __align__(16) float Bt[BK][68];

    const int tid = threadIdx.x;
    const int tn  = tid & 15;   // col group: cols n0 + tn*4 + 0..3
    const int tb  = tid >> 4;   // row group: rows tb*4 + 0..3
    float acc[4][4] = {};

    for (int c = 0; c < KSPAN / BK; ++c) {
        const int kc = k0  + c * BK;
        const int kw = kw0 + c * BK;
        {   // stage A chunk: A[b][kc..kc+31] -> At[kk][b] (transpose in LDS)
            const int s = (tid & 7) * 4;
            const int b = tid >> 3;            // 0..31, plus b+32
            float4 v0 = *(const float4*)(Asrc + (size_t)b * HID + kc + s);
            float4 v1 = *(const float4*)(Asrc + (size_t)(b + 32) * HID + kc + s);
            At[s + 0][b] = v0.x; At[s + 1][b] = v0.y;
            At[s + 2][b] = v0.z; At[s + 3][b] = v0.w;
            At[s + 0][b + 32] = v1.x; At[s + 1][b + 32] = v1.y;
            At[s + 2][b + 32] = v1.z; At[s + 3][b + 32] = v1.w;
        }
        {   // stage W chunk: W[kw+r][n0..n0+63] -> Bt[r][*]
            const int r = tid >> 4;            // 0..15, plus r+16
            *(float4*)&Bt[r][tn * 4] =
                *(const float4*)(W + (size_t)(kw + r) * G4 + n0 + tn * 4);
            *(float4*)&Bt[r + 16][tn * 4] =
                *(const float4*)(W + (size_t)(kw + r + 16) * G4 + n0 + tn * 4);
        }
        __syncthreads();
        #pragma unroll
        for (int kk = 0; kk < BK; ++kk) {
            const float4 av = *(const float4*)&At[kk][tb * 4];
            const float4 bv = *(const float4*)&Bt[kk][tn * 4];
            acc[0][0] += av.x * bv.x; acc[0][1] += av.x * bv.y;
            acc[0][2] += av.x * bv.z; acc[0][3] += av.x * bv.w;
            acc[1][0] += av.y * bv.x; acc[1][1] += av.y * bv.y;
            acc[1][2] += av.y * bv.z; acc[1][3] += av.y * bv.w;
            acc[2][0] += av.z * bv.x; acc[2][1] += av.z * bv.y;
            acc[2][2] += av.z * bv.z; acc[2][3] += av.z * bv.w;
            acc[3][0] += av.w * bv.x; acc[3][1] += av.w * bv.y;
            acc[3][2] += av.w * bv.z; acc[3][3] += av.w * bv.w;
        }
        __syncthreads();
    }
    #pragma unroll
    for (int i = 0; i < 4; ++i) {
        float4 v;
        v.x = acc[i][0]; v.y = acc[i][1]; v.z = acc[i][2]; v.w = acc[i][3];
        *(float4*)(P + (size_t)(tb * 4 + i) * G4 + n0 + tn * 4) = v;
    }
}

// ---------------------------------------------------------------------------
// Reduce 16 K-slice partials + bias, apply LSTM cell (gate order f,i,g,o).
// Blocks 0..255 -> layer0, 256..511 -> layer1.
// ---------------------------------------------------------------------------
__global__ __launch_bounds__(256) void reduce_step(
    const float* __restrict__ part,
    const float* __restrict__ bias0, const float* __restrict__ bias1,
    float* __restrict__ h0w, float* __restrict__ c0,
    float* __restrict__ h1w, float* __restrict__ c1,
    float* __restrict__ out_t, int act0, int act1)
{
    const int layer = (blockIdx.x >= 256) ? 1 : 0;
    if (layer ? !act1 : !act0) return;

    const int e  = (blockIdx.x & 255) * 256 + threadIdx.x;  // 0..65535
    const int b  = e >> 10;
    const int hj = e & (HID - 1);

    const float* __restrict__ P    = part + (size_t)layer * PART_L;
    const float* __restrict__ bias = layer ? bias1 : bias0;

    float g[4];
    #pragma unroll
    for (int q = 0; q < 4; ++q) {
        const int j = q * HID + hj;
        float s = bias[j];
        #pragma unroll
        for (int ksl = 0; ksl < KSLICES; ++ksl)
            s += P[(size_t)ksl * (BATCH * G4) + (size_t)b * G4 + j];
        g[q] = s;
    }
    const float f  = sigf(g[0]);
    const float i  = sigf(g[1]);
    const float gg = tanhf(g[2]);
    const float o  = sigf(g[3]);

    float* __restrict__ c = layer ? c1 : c0;
    const float cn = f * c[e] + i * gg;
    c[e] = cn;
    const float hn = o * tanhf(cn);
    if (layer) { h1w[e] = hn; out_t[e] = hn; }
    else       { h0w[e] = hn; }
}

// Final h_n = [h0_fin, h1_fin], c_n = [c0, c1] appended after output.
__global__ __launch_bounds__(256) void finalize(
    const float* __restrict__ h0f, const float* __restrict__ h1f,
    const float* __restrict__ c0,  const float* __restrict__ c1,
    float* __restrict__ dst)
{
    const int i = blockIdx.x * 256 + threadIdx.x;  // 0..65535
    dst[i]             = h0f[i];
    dst[STATE + i]     = h1f[i];
    dst[2 * STATE + i] = c0[i];
    dst[3 * STATE + i] = c1[i];
}

extern "C" void kernel_launch(void* const* d_in, const int* in_sizes, int n_in,
                              void* d_out, int out_size, void* d_ws, size_t ws_size,
                              hipStream_t stream)
{
    const float* x    = (const float*)d_in[0];   // [512][64][1024]
    const float* W    = (const float*)d_in[1];   // [2][2048][4096]
    const float* bias = (const float*)d_in[2];   // [2][4096]
    float* out = (float*)d_out;                  // output + h_n + c_n
    float* ws  = (float*)d_ws;

    // ws layout (floats): h0 double-buffer, c0, h1, c1, then GEMM partials.
    float* h0b[2] = { ws, ws + STATE };
    float* c0   = ws + 2 * STATE;
    float* h1   = ws + 3 * STATE;
    float* c1   = ws + 4 * STATE;
    float* part = ws + 5 * STATE;                // 2 * 16 * 64 * 4096 floats (~33.5 MB)

    // zero the recurrent state (d_ws is poisoned before every call)
    hipMemsetAsync(ws, 0, (size_t)5 * STATE * sizeof(float), stream);

    const float* W0  = W;
    const float* W1  = W + (size_t)KTOT * G4;
    const float* bs0 = bias;
    const float* bs1 = bias + G4;

    for (int d = 0; d <= T_STEPS; ++d) {
        const int act0 = (d < T_STEPS) ? 1 : 0;  // layer0 runs t=d
        const int act1 = (d >= 1) ? 1 : 0;       // layer1 runs t=d-1
        const float* A0x   = x + (size_t)(act0 ? d : 0) * STATE;
        const float* hprev0 = h0b[(d + 1) & 1];  // h0 written at step d-1 (zeros at d=0)
        float*       h0w    = h0b[d & 1];

        gemm_step<<<2048, 256, 0, stream>>>(A0x, hprev0, W0,
                                            hprev0, h1, W1,
                                            part, act0, act1);
        float* out_t = out + (size_t)(act1 ? d - 1 : 0) * STATE;
        reduce_step<<<512, 256, 0, stream>>>(part, bs0, bs1,
                                             h0w, c0, h1, c1, out_t, act0, act1);
    }
    // h0 final buffer: written at d=511 -> h0b[511&1] = h0b[1]
    finalize<<<STATE / 256, 256, 0, stream>>>(h0b[1], h1, c0, c1,
                                              out + (size_t)T_STEPS * STATE);
}

// Round 3
// 6463.126 us; speedup vs baseline: 3.3066x; 3.3066x over previous
//
#include <hip/hip_runtime.h>
#include <math.h>

// LSTM T=512, B=64, H=1024, L=2.
// Diagonal schedule, ONE fused kernel per diagonal step:
//   GEMM (fp16 MFMA 16x16x32, fp32 accum, K-split over 8 waves, frag-direct
//   global loads from pre-packed W) -> LDS K-reduction -> fused LSTM cell.
// Phase 0: pack W to fp16 MFMA-frag layout; convert x[0] to fp16; zero state.

#define T_STEPS 512
#define HID     1024
#define STATE   65536            // 64*1024
#define G4      4096

typedef _Float16 f16;
typedef _Float16 f16x8 __attribute__((ext_vector_type(8)));
typedef float    f32x4 __attribute__((ext_vector_type(4)));

__device__ __forceinline__ float sigf(float x) { return 1.0f / (1.0f + __expf(-x)); }

// ---------------------------------------------------------------------------
// Pack W [2][2048][4096] fp32 -> fp16 MFMA B-frags.
// Frag (l, nt, ksg): lane holds B[k = ksg*32 + (lane>>4)*8 + j][n = nt*16 + (lane&15)],
// j=0..7, stored contiguously: packW[((l*256+nt)*64+ksg)*512 + lane*8 + j].
// ---------------------------------------------------------------------------
__global__ __launch_bounds__(256) void pack_w(const float* __restrict__ W,
                                              f16* __restrict__ packW)
{
    const size_t g = (size_t)blockIdx.x * 256 + threadIdx.x;  // 2*256*64*64 threads
    const int lane = g & 63;
    const int ksg  = (g >> 6) & 63;
    const int nt   = (g >> 12) & 255;
    const int l    = (int)(g >> 20);
    const int k    = ksg * 32 + ((lane >> 4) << 3);
    const int n    = nt * 16 + (lane & 15);
    const float* src = W + ((size_t)l * 2048 + k) * G4 + n;
    f16x8 v;
    #pragma unroll
    for (int j = 0; j < 8; ++j) v[j] = (f16)src[(size_t)j * G4];
    *(f16x8*)(packW + g * 8) = v;
}

__global__ __launch_bounds__(256) void cvt_x0(const float* __restrict__ x,
                                              f16* __restrict__ xf)
{
    const int i = blockIdx.x * 256 + threadIdx.x;   // 65536 threads
    xf[i] = (f16)x[i];
}

// ---------------------------------------------------------------------------
// Fused step kernel. Grid = 256 WGs x 512 threads (8 waves).
// WG -> (layer = bid>>7, mhalf = (bid>>6)&1, strip = bid&63).
// WG output tile: rows b = mhalf*32..+31, cols = 4 gates x [strip*16..+15].
// Wave w owns K-slice [w*256, (w+1)*256): waves 0-3 read the x-part operand,
// waves 4-7 the h-part. Per kstep: 2 A-frags + 4 B-frags -> 8 MFMAs.
// ---------------------------------------------------------------------------
__global__ __launch_bounds__(512) void step_kernel(
    const f16* __restrict__ packW, const float* __restrict__ bias,
    const float* __restrict__ x,
    f16* __restrict__ xf16_0, f16* __restrict__ xf16_1,
    f16* __restrict__ h0_0, f16* __restrict__ h0_1,
    f16* __restrict__ h1_0, f16* __restrict__ h1_1,
    float* __restrict__ h0f32,
    float* __restrict__ c0, float* __restrict__ c1,
    float* __restrict__ out, int d)
{
    const int layer = blockIdx.x >> 7;
    const int mhalf = (blockIdx.x >> 6) & 1;
    const int strip = blockIdx.x & 63;
    const int act   = layer ? (d >= 1) : (d < T_STEPS);
    const int tid   = threadIdx.x;

    __shared__ float red[8][32][68];   // [k-slice][m-row][4 gates x 16 (+pad)]

    const f16* xf_cur  = (d & 1) ? xf16_1 : xf16_0;          // x[d] fp16
    const f16* h0_prev = ((d + 1) & 1) ? h0_1 : h0_0;        // h0[d-1]
    const f16* h1_prev = ((d + 1) & 1) ? h1_1 : h1_0;        // h1[d-2]
    f16* h0_new = (d & 1) ? h0_1 : h0_0;
    f16* h1_new = (d & 1) ? h1_1 : h1_0;

    if (act) {
        const int w = tid >> 6, lane = tid & 63;
        // A operand: layer0 = [x_t, h0_prev], layer1 = [h0_prev, h1_prev]
        const f16* Abase = (layer == 0) ? ((w < 4) ? xf_cur : h0_prev)
                                        : ((w < 4) ? h0_prev : h1_prev);
        const int kloc = (w & 3) * 256;            // k offset within Abase
        const int am = lane & 15, ak = (lane >> 4) * 8;
        const int abrow = mhalf * 32 + am;         // A rows: abrow, +16

        f32x4 acc[2][4];
        #pragma unroll
        for (int mt = 0; mt < 2; ++mt)
            #pragma unroll
            for (int g = 0; g < 4; ++g) acc[mt][g] = (f32x4){0.f, 0.f, 0.f, 0.f};

        // B frag stream base: frag = ((layer*256 + g*64 + strip)*64 + w*8 + ks)
        const size_t fb = ((size_t)layer * 256 + strip) * 64 + w * 8;

        for (int ks = 0; ks < 8; ++ks) {
            const int kk = kloc + ks * 32 + ak;
            f16x8 a[2], b[4];
            #pragma unroll
            for (int mt = 0; mt < 2; ++mt)
                a[mt] = *(const f16x8*)(Abase + (size_t)(abrow + mt * 16) * HID + kk);
            #pragma unroll
            for (int g = 0; g < 4; ++g)
                b[g] = *(const f16x8*)(packW + (fb + (size_t)g * 64 * 64 + ks) * 512
                                       + lane * 8);
            #pragma unroll
            for (int mt = 0; mt < 2; ++mt)
                #pragma unroll
                for (int g = 0; g < 4; ++g)
                    acc[mt][g] = __builtin_amdgcn_mfma_f32_16x16x32_f16(
                        a[mt], b[g], acc[mt][g], 0, 0, 0);
        }
        // spill partial tiles to LDS for K-reduction
        const int rbase = (lane >> 4) * 4;
        const int cn    = lane & 15;
        #pragma unroll
        for (int mt = 0; mt < 2; ++mt)
            #pragma unroll
            for (int g = 0; g < 4; ++g)
                #pragma unroll
                for (int r = 0; r < 4; ++r)
                    red[w][mt * 16 + rbase + r][g * 16 + cn] = acc[mt][g][r];
    }
    __syncthreads();

    if (act) {
        // one cell element per thread: 32 rows x 16 cols
        const int jq   = tid & 15;
        const int mrow = tid >> 4;          // 0..31
        const int b    = mhalf * 32 + mrow;
        const int jgl  = strip * 16 + jq;

        float gate[4];
        #pragma unroll
        for (int g = 0; g < 4; ++g) {
            float s = bias[layer * G4 + g * HID + jgl];
            #pragma unroll
            for (int w = 0; w < 8; ++w) s += red[w][mrow][g * 16 + jq];
            gate[g] = s;
        }
        const float f  = sigf(gate[0]);
        const float i  = sigf(gate[1]);
        const float gg = tanhf(gate[2]);
        const float o  = sigf(gate[3]);

        const int e = b * HID + jgl;
        float* c = layer ? c1 : c0;
        const float cn = f * c[e] + i * gg;
        c[e] = cn;
        const float hn = o * tanhf(cn);
        if (layer) { h1_new[e] = (f16)hn; out[(size_t)(d - 1) * STATE + e] = hn; }
        else       { h0_new[e] = (f16)hn; h0f32[e] = hn; }
    }

    // convert x[d+1] -> fp16 for the next step (all WGs, half the threads)
    if (d + 1 < T_STEPS) {
        const int idx = blockIdx.x * 512 + tid;
        if (idx < STATE) {
            f16* xdst = ((d + 1) & 1) ? xf16_1 : xf16_0;
            xdst[idx] = (f16)x[(size_t)(d + 1) * STATE + idx];
        }
    }
}

__global__ __launch_bounds__(256) void finalize(
    const float* __restrict__ h0f32, const float* __restrict__ c0,
    const float* __restrict__ c1, float* __restrict__ out)
{
    const int i = blockIdx.x * 256 + threadIdx.x;  // 65536
    float* dst = out + (size_t)T_STEPS * STATE;
    dst[i]             = h0f32[i];
    dst[STATE + i]     = out[(size_t)(T_STEPS - 1) * STATE + i];
    dst[2 * STATE + i] = c0[i];
    dst[3 * STATE + i] = c1[i];
}

extern "C" void kernel_launch(void* const* d_in, const int* in_sizes, int n_in,
                              void* d_out, int out_size, void* d_ws, size_t ws_size,
                              hipStream_t stream)
{
    const float* x    = (const float*)d_in[0];
    const float* W    = (const float*)d_in[1];
    const float* bias = (const float*)d_in[2];
    float* out = (float*)d_out;

    // ws layout
    f16* packW  = (f16*)d_ws;                  // 16,777,216 f16 (32 MB)
    f16* xf16_0 = packW + (size_t)2 * 256 * 64 * 512;
    f16* xf16_1 = xf16_0 + STATE;
    f16* h0_0   = xf16_1 + STATE;
    f16* h0_1   = h0_0 + STATE;
    f16* h1_0   = h0_1 + STATE;
    f16* h1_1   = h1_0 + STATE;
    float* h0f32 = (float*)(h1_1 + STATE);
    float* c0    = h0f32 + STATE;
    float* c1    = c0 + STATE;

    // zero h0_0..c1 (contiguous): 4*128KB + 3*256KB
    hipMemsetAsync(h0_0, 0, (size_t)4 * STATE * 2 + (size_t)3 * STATE * 4, stream);
    pack_w<<<8192, 256, 0, stream>>>(W, packW);
    cvt_x0<<<STATE / 256, 256, 0, stream>>>(x, xf16_0);

    for (int d = 0; d <= T_STEPS; ++d) {
        step_kernel<<<256, 512, 0, stream>>>(packW, bias, x,
                                             xf16_0, xf16_1,
                                             h0_0, h0_1, h1_0, h1_1,
                                             h0f32, c0, c1, out, d);
    }
    finalize<<<STATE / 256, 256, 0, stream>>>(h0f32, c0, c1, out);
}